// Round 1
// baseline (455.434 us; speedup 1.0000x reference)
//
#include <hip/hip_runtime.h>

#define NEXP 8
#define NTOK 1024
#define HID 2048
#define ITR 1024

typedef __attribute__((ext_vector_type(8))) short short8;
typedef __attribute__((ext_vector_type(4))) float f32x4;

__device__ __forceinline__ unsigned short f2bf(float f) {
  unsigned u = __float_as_uint(f);
  u += 0x7fffu + ((u >> 16) & 1u);
  return (unsigned short)(u >> 16);
}

__device__ __forceinline__ void gl_lds16(const void* g, void* l) {
  __builtin_amdgcn_global_load_lds(
      (const __attribute__((address_space(1))) unsigned int*)g,
      (__attribute__((address_space(3))) unsigned int*)l, 16, 0, 0);
}

// ---------------- setup: zero out + x fp32->bf16 ----------------
__global__ __launch_bounds__(256) void k_setup(const float* __restrict__ x,
                                               unsigned int* __restrict__ xb,
                                               float* __restrict__ out) {
  int i = blockIdx.x * 256 + threadIdx.x;   // 524288 threads, 4 elems each
  f32x4 z = {0.f, 0.f, 0.f, 0.f};
  *(f32x4*)(out + (size_t)i * 4) = z;
  f32x4 v = *(const f32x4*)(x + (size_t)i * 4);
  unsigned lo = (unsigned)f2bf(v[0]) | ((unsigned)f2bf(v[1]) << 16);
  unsigned hi = (unsigned)f2bf(v[2]) | ((unsigned)f2bf(v[3]) << 16);
  xb[(size_t)i * 2] = lo;
  xb[(size_t)i * 2 + 1] = hi;
}

// ---------------- router: top-2 + per-expert lists ----------------
__global__ __launch_bounds__(1024) void k_router(const float* __restrict__ rp,
                                                 int* __restrict__ counts,
                                                 int* __restrict__ toklist,
                                                 float* __restrict__ wlist) {
  __shared__ int c[NEXP];
  int n = threadIdx.x;
  if (n < NEXP) c[n] = 0;
  __syncthreads();
  float r[NEXP];
#pragma unroll
  for (int e = 0; e < NEXP; ++e) r[e] = rp[n * NEXP + e];
  int i1 = 0;
  float m1 = r[0];
#pragma unroll
  for (int e = 1; e < NEXP; ++e)
    if (r[e] > m1) { m1 = r[e]; i1 = e; }
  int i2 = -1;
  float m2 = -3.4e38f;
#pragma unroll
  for (int e = 0; e < NEXP; ++e)
    if (e != i1 && r[e] > m2) { m2 = r[e]; i2 = e; }
  // renormalized top-2 softmax == 2-way softmax of top-2 logits
  float p1 = 1.f / (1.f + __expf(m2 - m1));
  float p2 = 1.f - p1;
  int s1 = atomicAdd(&c[i1], 1);
  toklist[i1 * NTOK + s1] = n;
  wlist[i1 * NTOK + s1] = p1;
  int s2 = atomicAdd(&c[i2], 1);
  toklist[i2 * NTOK + s2] = n;
  wlist[i2 * NTOK + s2] = p2;
  __syncthreads();
  if (n < NEXP) counts[n] = c[n];
}

// ---------------- grouped GEMM fc1/fc3 + swiglu ----------------
// W LDS layout: [n][k] bf16, 16B blocks XOR-swizzled by key(n)
__global__ __launch_bounds__(256) void k_gemm13(
    const float* __restrict__ fc1, const float* __restrict__ fc3,
    const unsigned short* __restrict__ xb, const int* __restrict__ counts,
    const int* __restrict__ toklist, unsigned short* __restrict__ act) {
  const int mtile = blockIdx.x, ntile = blockIdx.y, e = blockIdx.z;
  const int cnt = counts[e];
  const int mbase = mtile * 128;
  if (mbase >= cnt) return;
  const int n0 = ntile * 128;

  __shared__ __align__(16) unsigned short lds[3 * 128 * 64];
  unsigned short* ldsA = lds;
  unsigned short* ldsW1 = lds + 128 * 64;
  unsigned short* ldsW3 = lds + 2 * 128 * 64;

  const int tid = threadIdx.x;
  const int lane = tid & 63, w = tid >> 6;

  // A-stage: 4 chunks (16B) per thread, source pre-XOR-swizzled (dest linear)
  const unsigned short* asrc[4];
#pragma unroll
  for (int p = 0; p < 4; ++p) {
    int cch = (p * 4 + w) * 64 + lane;
    int r = cch >> 3, b = cch & 7;
    int bs = b ^ (r & 7);
    int row = mbase + r;
    int tok = toklist[e * NTOK + ((row < cnt) ? row : 0)];
    asrc[p] = xb + (size_t)tok * HID + bs * 8;
  }

  const int nq = (tid & 31) * 4;
  const int kp = tid >> 5;  // 0..7
  const float* w1base = fc1 + (size_t)e * HID * ITR + n0 + nq;
  const float* w3base = fc3 + (size_t)e * HID * ITR + n0 + nq;

  const int r0 = (w >> 1) * 64;
  const int c0 = (w & 1) * 64;

  f32x4 acc1[4][4], acc3[4][4];
#pragma unroll
  for (int mi = 0; mi < 4; ++mi)
#pragma unroll
    for (int ni = 0; ni < 4; ++ni) {
      acc1[mi][ni] = (f32x4){0.f, 0.f, 0.f, 0.f};
      acc3[mi][ni] = (f32x4){0.f, 0.f, 0.f, 0.f};
    }

  for (int kt = 0; kt < HID / 64; ++kt) {
    const int k0 = kt * 64;
#pragma unroll
    for (int p = 0; p < 4; ++p)
      gl_lds16(asrc[p] + k0, ldsA + (p * 4 + w) * 512);
#pragma unroll
    for (int p = 0; p < 4; ++p) {
      int k = (p * 8 + kp) * 2;  // even, 0..62
      const float* g1 = w1base + (size_t)(k0 + k) * ITR;
      const float* g3 = w3base + (size_t)(k0 + k) * ITR;
      f32x4 a1 = *(const f32x4*)g1;
      f32x4 b1 = *(const f32x4*)(g1 + ITR);
      f32x4 a3 = *(const f32x4*)g3;
      f32x4 b3 = *(const f32x4*)(g3 + ITR);
#pragma unroll
      for (int j = 0; j < 4; ++j) {
        int n = nq + j;
        int key = ((n >> 2) & 7) ^ ((n & 3) << 1);
        int boff = n * 128 + (((2 * k) & 15) | ((((2 * k) >> 4) ^ key) << 4));
        *(unsigned*)((char*)ldsW1 + boff) =
            (unsigned)f2bf(a1[j]) | ((unsigned)f2bf(b1[j]) << 16);
        *(unsigned*)((char*)ldsW3 + boff) =
            (unsigned)f2bf(a3[j]) | ((unsigned)f2bf(b3[j]) << 16);
      }
    }
    __syncthreads();
#pragma unroll
    for (int s = 0; s < 2; ++s) {
      short8 af[4];
#pragma unroll
      for (int mi = 0; mi < 4; ++mi) {
        int row = r0 + mi * 16 + (lane & 15);
        int kb = s * 4 + (lane >> 4);
        af[mi] = *(const short8*)((const char*)ldsA + row * 128 +
                                  ((kb ^ (row & 7)) << 4));
      }
#pragma unroll
      for (int ni = 0; ni < 4; ++ni) {
        int n = c0 + ni * 16 + (lane & 15);
        int kb = s * 4 + (lane >> 4);
        int key = ((n >> 2) & 7) ^ ((n & 3) << 1);
        int off = n * 128 + ((kb ^ key) << 4);
        short8 w1 = *(const short8*)((const char*)ldsW1 + off);
        short8 w3 = *(const short8*)((const char*)ldsW3 + off);
#pragma unroll
        for (int mi = 0; mi < 4; ++mi) {
          acc1[mi][ni] = __builtin_amdgcn_mfma_f32_16x16x32_bf16(
              af[mi], w1, acc1[mi][ni], 0, 0, 0);
          acc3[mi][ni] = __builtin_amdgcn_mfma_f32_16x16x32_bf16(
              af[mi], w3, acc3[mi][ni], 0, 0, 0);
        }
      }
    }
    __syncthreads();
  }

  // epilogue: swiglu -> LDS repack -> coalesced bf16 store
  unsigned short* lact = lds;  // [128][136]
#pragma unroll
  for (int mi = 0; mi < 4; ++mi)
#pragma unroll
    for (int ni = 0; ni < 4; ++ni)
#pragma unroll
      for (int r = 0; r < 4; ++r) {
        float h1 = acc1[mi][ni][r], h3 = acc3[mi][ni][r];
        float a = h1 * (1.f / (1.f + __expf(-h1))) * h3;
        int row = r0 + mi * 16 + (lane >> 4) * 4 + r;
        int col = c0 + ni * 16 + (lane & 15);
        lact[row * 136 + col] = f2bf(a);
      }
  __syncthreads();
  const int trow = tid >> 4, tcol = (tid & 15) * 8;
#pragma unroll
  for (int pp = 0; pp < 8; ++pp) {
    int row = pp * 16 + trow;
    if (mbase + row < cnt)
      *(short8*)(act + ((size_t)e * NTOK + mbase + row) * ITR + n0 + tcol) =
          *(const short8*)&lact[row * 136 + tcol];
  }
}

// ---------------- grouped GEMM fc2 + scaled atomic combine ----------------
__global__ __launch_bounds__(256) void k_gemm2(
    const float* __restrict__ fc2, const unsigned short* __restrict__ act,
    const int* __restrict__ counts, const int* __restrict__ toklist,
    const float* __restrict__ wlist, float* __restrict__ out) {
  const int mtile = blockIdx.x, ntile = blockIdx.y, e = blockIdx.z;
  const int cnt = counts[e];
  const int mbase = mtile * 128;
  if (mbase >= cnt) return;
  const int n0 = ntile * 128;

  __shared__ __align__(16) unsigned short lds[2 * 128 * 64];
  unsigned short* ldsA = lds;
  unsigned short* ldsW = lds + 128 * 64;
  __shared__ float pbuf[128];
  __shared__ int tbuf[128];

  const int tid = threadIdx.x;
  const int lane = tid & 63, w = tid >> 6;

  if (tid < 128) {
    int row = mbase + tid;
    bool v = row < cnt;
    pbuf[tid] = v ? wlist[e * NTOK + row] : 0.f;
    tbuf[tid] = v ? toklist[e * NTOK + row] : 0;
  }

  const unsigned short* asrc[4];
#pragma unroll
  for (int p = 0; p < 4; ++p) {
    int cch = (p * 4 + w) * 64 + lane;
    int r = cch >> 3, b = cch & 7;
    int bs = b ^ (r & 7);
    asrc[p] = act + ((size_t)e * NTOK + mbase + r) * ITR + bs * 8;
  }

  const int nq = (tid & 31) * 4;
  const int kp = tid >> 5;
  const float* wbase = fc2 + (size_t)e * ITR * HID + n0 + nq;

  const int r0 = (w >> 1) * 64;
  const int c0 = (w & 1) * 64;

  f32x4 acc[4][4];
#pragma unroll
  for (int mi = 0; mi < 4; ++mi)
#pragma unroll
    for (int ni = 0; ni < 4; ++ni) acc[mi][ni] = (f32x4){0.f, 0.f, 0.f, 0.f};

  for (int kt = 0; kt < ITR / 64; ++kt) {
    const int k0 = kt * 64;
#pragma unroll
    for (int p = 0; p < 4; ++p)
      gl_lds16(asrc[p] + k0, ldsA + (p * 4 + w) * 512);
#pragma unroll
    for (int p = 0; p < 4; ++p) {
      int k = (p * 8 + kp) * 2;
      const float* g = wbase + (size_t)(k0 + k) * HID;
      f32x4 a = *(const f32x4*)g;
      f32x4 b = *(const f32x4*)(g + HID);
#pragma unroll
      for (int j = 0; j < 4; ++j) {
        int n = nq + j;
        int key = ((n >> 2) & 7) ^ ((n & 3) << 1);
        int boff = n * 128 + (((2 * k) & 15) | ((((2 * k) >> 4) ^ key) << 4));
        *(unsigned*)((char*)ldsW + boff) =
            (unsigned)f2bf(a[j]) | ((unsigned)f2bf(b[j]) << 16);
      }
    }
    __syncthreads();
#pragma unroll
    for (int s = 0; s < 2; ++s) {
      short8 af[4];
#pragma unroll
      for (int mi = 0; mi < 4; ++mi) {
        int row = r0 + mi * 16 + (lane & 15);
        int kb = s * 4 + (lane >> 4);
        af[mi] = *(const short8*)((const char*)ldsA + row * 128 +
                                  ((kb ^ (row & 7)) << 4));
      }
#pragma unroll
      for (int ni = 0; ni < 4; ++ni) {
        int n = c0 + ni * 16 + (lane & 15);
        int kb = s * 4 + (lane >> 4);
        int key = ((n >> 2) & 7) ^ ((n & 3) << 1);
        int off = n * 128 + ((kb ^ key) << 4);
        short8 wf = *(const short8*)((const char*)ldsW + off);
#pragma unroll
        for (int mi = 0; mi < 4; ++mi)
          acc[mi][ni] = __builtin_amdgcn_mfma_f32_16x16x32_bf16(
              af[mi], wf, acc[mi][ni], 0, 0, 0);
      }
    }
    __syncthreads();
  }

  // epilogue: scale by prob, atomic combine (exactly 2 adds per out element)
#pragma unroll
  for (int mi = 0; mi < 4; ++mi)
#pragma unroll
    for (int r = 0; r < 4; ++r) {
      int lr = r0 + mi * 16 + (lane >> 4) * 4 + r;
      if (mbase + lr < cnt) {
        float pv = pbuf[lr];
        float* orow = out + (size_t)tbuf[lr] * HID + n0 + c0 + (lane & 15);
#pragma unroll
        for (int ni = 0; ni < 4; ++ni)
          atomicAdd(orow + ni * 16, acc[mi][ni][r] * pv);
      }
    }
}

extern "C" void kernel_launch(void* const* d_in, const int* in_sizes, int n_in,
                              void* d_out, int out_size, void* d_ws,
                              size_t ws_size, hipStream_t stream) {
  (void)in_sizes; (void)n_in; (void)out_size; (void)ws_size;
  const float* x = (const float*)d_in[0];
  const float* rp = (const float*)d_in[1];
  const float* fc1 = (const float*)d_in[2];
  const float* fc2 = (const float*)d_in[3];
  const float* fc3 = (const float*)d_in[4];
  float* out = (float*)d_out;
  char* ws = (char*)d_ws;

  int* counts = (int*)ws;                                  // 32 B
  int* toklist = (int*)(ws + 1024);                        // 32 KB
  float* wlist = (float*)(ws + 1024 + NEXP * NTOK * 4);    // 32 KB
  unsigned short* xb = (unsigned short*)(ws + 1024 + 2 * NEXP * NTOK * 4);
  unsigned short* act = xb + (size_t)NTOK * HID;           // 16 MB bf16

  k_setup<<<2048, 256, 0, stream>>>(x, (unsigned int*)xb, out);
  k_router<<<1, 1024, 0, stream>>>(rp, counts, toklist, wlist);
  k_gemm13<<<dim3(8, 8, NEXP), 256, 0, stream>>>(fc1, fc3, xb, counts, toklist,
                                                 act);
  k_gemm2<<<dim3(8, 16, NEXP), 256, 0, stream>>>(fc2, act, counts, toklist,
                                                 wlist, out);
}

// Round 2
// 370.829 us; speedup vs baseline: 1.2282x; 1.2282x over previous
//
#include <hip/hip_runtime.h>

#define NEXP 8
#define NTOK 1024
#define HID 2048
#define ITR 1024

typedef __attribute__((ext_vector_type(8))) short short8;
typedef __attribute__((ext_vector_type(4))) float f32x4;

__device__ __forceinline__ unsigned short f2bf(float f) {
  unsigned u = __float_as_uint(f);
  u += 0x7fffu + ((u >> 16) & 1u);
  return (unsigned short)(u >> 16);
}

__device__ __forceinline__ void gl_lds16(const void* g, void* l) {
  __builtin_amdgcn_global_load_lds(
      (const __attribute__((address_space(1))) unsigned int*)g,
      (__attribute__((address_space(3))) unsigned int*)l, 16, 0, 0);
}

// ---------------- setup: zero out + x fp32->bf16 ----------------
__global__ __launch_bounds__(256) void k_setup(const float* __restrict__ x,
                                               unsigned int* __restrict__ xb,
                                               float* __restrict__ out) {
  int i = blockIdx.x * 256 + threadIdx.x;  // 524288 threads, 4 f32 each
  f32x4 z = {0.f, 0.f, 0.f, 0.f};
  *(f32x4*)(out + (size_t)i * 4) = z;
  f32x4 v = *(const f32x4*)(x + (size_t)i * 4);
  xb[(size_t)i * 2] = (unsigned)f2bf(v[0]) | ((unsigned)f2bf(v[1]) << 16);
  xb[(size_t)i * 2 + 1] = (unsigned)f2bf(v[2]) | ((unsigned)f2bf(v[3]) << 16);
}

// ---------------- router: top-2, flat compacted lists ----------------
__global__ __launch_bounds__(1024) void k_router(const float* __restrict__ rp,
                                                 int* __restrict__ counts,
                                                 int* __restrict__ base,
                                                 int* __restrict__ toklist,
                                                 float* __restrict__ wlist) {
  __shared__ int c[NEXP];
  __shared__ int sb[NEXP];
  int n = threadIdx.x;
  if (n < NEXP) c[n] = 0;
  __syncthreads();
  float r[NEXP];
#pragma unroll
  for (int e = 0; e < NEXP; ++e) r[e] = rp[n * NEXP + e];
  int i1 = 0;
  float m1 = r[0];
#pragma unroll
  for (int e = 1; e < NEXP; ++e)
    if (r[e] > m1) { m1 = r[e]; i1 = e; }
  int i2 = -1;
  float m2 = -3.4e38f;
#pragma unroll
  for (int e = 0; e < NEXP; ++e)
    if (e != i1 && r[e] > m2) { m2 = r[e]; i2 = e; }
  float p1 = 1.f / (1.f + __expf(m2 - m1));
  float p2 = 1.f - p1;
  int s1 = atomicAdd(&c[i1], 1);
  int s2 = atomicAdd(&c[i2], 1);
  __syncthreads();
  if (n == 0) {
    int a = 0;
#pragma unroll
    for (int e = 0; e < NEXP; ++e) { sb[e] = a; a += c[e]; }
  }
  __syncthreads();
  int q1 = sb[i1] + s1;
  toklist[q1] = n; wlist[q1] = p1;
  int q2 = sb[i2] + s2;
  toklist[q2] = n; wlist[q2] = p2;
  if (n < NEXP) { counts[n] = c[n]; base[n] = sb[n]; }
}

// ---------------- transpose-convert: fp32 [R][C] -> bf16 [C][R] ----------
__global__ __launch_bounds__(256) void k_transcvt(const float* __restrict__ in,
                                                  unsigned short* __restrict__ out,
                                                  int R, int C) {
  const int e = blockIdx.z;
  const float* src = in + (size_t)e * R * C;
  unsigned short* dst = out + (size_t)e * R * C;
  const int r0 = blockIdx.x * 64, c0 = blockIdx.y * 64;
  __shared__ unsigned short t[64][66];
  const int tid = threadIdx.x;
  const int r = tid >> 2, q = tid & 3;
  const float* p = src + (size_t)(r0 + r) * C + c0 + q * 4;
#pragma unroll
  for (int i = 0; i < 4; ++i) {
    f32x4 v = *(const f32x4*)(p + i * 16);
#pragma unroll
    for (int j = 0; j < 4; ++j) t[r][i * 16 + q * 4 + j] = f2bf(v[j]);
  }
  __syncthreads();
  const int cc = tid >> 2, rq = (tid & 3) * 16;
  unsigned short tmp[16];
#pragma unroll
  for (int i = 0; i < 16; ++i) tmp[i] = t[rq + i][cc];
  unsigned short* qo = dst + (size_t)(c0 + cc) * R + r0 + rq;
  *(short8*)qo = *(const short8*)tmp;
  *(short8*)(qo + 8) = *(const short8*)(tmp + 8);
}

// ---------------- grouped GEMM fc1/fc3 + swiglu (64x64 tile, dbuf) -------
__global__ __launch_bounds__(256, 2) void k_gemm13(
    const unsigned short* __restrict__ w1t, const unsigned short* __restrict__ w3t,
    const unsigned short* __restrict__ xb, const int* __restrict__ counts,
    const int* __restrict__ base, const int* __restrict__ toklist,
    unsigned short* __restrict__ act) {
  const int e = blockIdx.z;
  const int cnt = counts[e];
  const int mbase = blockIdx.x * 64;
  if (mbase >= cnt) return;
  const int n0 = blockIdx.y * 64;
  const int rbase = base[e];

  __shared__ __align__(16) unsigned short lds[2 * 3 * 4096];  // dbuf x (A,W1,W3)
  const int tid = threadIdx.x;
  const int lane = tid & 63, w = tid >> 6;

  // staging sources (XOR-preswizzled k-offset, linear LDS dest)
  const unsigned short *srcA[2], *srcW1[2], *srcW3[2];
  int dof[2];
#pragma unroll
  for (int i = 0; i < 2; ++i) {
    int cc = i * 256 + tid;
    int r = cc >> 3, b = cc & 7;
    int ko = (b ^ (r & 7)) * 8;
    int row = mbase + r;
    int tok = toklist[rbase + ((row < cnt) ? row : (cnt - 1))];
    srcA[i] = xb + (size_t)tok * HID + ko;
    srcW1[i] = w1t + ((size_t)e * ITR + n0 + r) * HID + ko;
    srcW3[i] = w3t + ((size_t)e * ITR + n0 + r) * HID + ko;
    dof[i] = i * 2048 + w * 512;  // ushort units, wave-uniform
  }

  // fragment byte offsets within a tile
  int offA[2][2], offW[2][2];
#pragma unroll
  for (int mi = 0; mi < 2; ++mi)
#pragma unroll
    for (int s = 0; s < 2; ++s) {
      int rowA = (w >> 1) * 32 + mi * 16 + (lane & 15);
      int rowW = (w & 1) * 32 + mi * 16 + (lane & 15);
      int kb = s * 4 + (lane >> 4);
      offA[mi][s] = rowA * 128 + ((kb ^ (rowA & 7)) << 4);
      offW[mi][s] = rowW * 128 + ((kb ^ (rowW & 7)) << 4);
    }

  f32x4 acc1[2][2], acc3[2][2];
#pragma unroll
  for (int mi = 0; mi < 2; ++mi)
#pragma unroll
    for (int ni = 0; ni < 2; ++ni) {
      acc1[mi][ni] = (f32x4){0.f, 0.f, 0.f, 0.f};
      acc3[mi][ni] = (f32x4){0.f, 0.f, 0.f, 0.f};
    }

#define STAGE13(buf, kt)                                          \
  {                                                               \
    int k0 = (kt) * 64;                                           \
    unsigned short* Lb = lds + (buf) * 12288;                     \
    _Pragma("unroll") for (int i = 0; i < 2; ++i) {               \
      gl_lds16(srcA[i] + k0, Lb + dof[i]);                        \
      gl_lds16(srcW1[i] + k0, Lb + 4096 + dof[i]);                \
      gl_lds16(srcW3[i] + k0, Lb + 8192 + dof[i]);                \
    }                                                             \
  }

  STAGE13(0, 0);
  __syncthreads();
  int buf = 0;
  for (int kt = 0; kt < HID / 64; ++kt) {
    if (kt + 1 < HID / 64) STAGE13(buf ^ 1, kt + 1);
    const char* LA = (const char*)lds + buf * 24576;
    const char* LW1 = LA + 8192;
    const char* LW3 = LA + 16384;
#pragma unroll
    for (int s = 0; s < 2; ++s) {
      short8 af[2], w1f[2], w3f[2];
#pragma unroll
      for (int mi = 0; mi < 2; ++mi) af[mi] = *(const short8*)(LA + offA[mi][s]);
#pragma unroll
      for (int ni = 0; ni < 2; ++ni) {
        w1f[ni] = *(const short8*)(LW1 + offW[ni][s]);
        w3f[ni] = *(const short8*)(LW3 + offW[ni][s]);
      }
#pragma unroll
      for (int ni = 0; ni < 2; ++ni)
#pragma unroll
        for (int mi = 0; mi < 2; ++mi) {
          acc1[mi][ni] = __builtin_amdgcn_mfma_f32_16x16x32_bf16(
              af[mi], w1f[ni], acc1[mi][ni], 0, 0, 0);
          acc3[mi][ni] = __builtin_amdgcn_mfma_f32_16x16x32_bf16(
              af[mi], w3f[ni], acc3[mi][ni], 0, 0, 0);
        }
    }
    __syncthreads();
    buf ^= 1;
  }

  // epilogue: swiglu -> LDS repack -> coalesced bf16 store to flat act
  unsigned short* lact = lds;  // [64][80]
#pragma unroll
  for (int mi = 0; mi < 2; ++mi)
#pragma unroll
    for (int ni = 0; ni < 2; ++ni)
#pragma unroll
      for (int rr = 0; rr < 4; ++rr) {
        float h1 = acc1[mi][ni][rr], h3 = acc3[mi][ni][rr];
        float a = h1 * (1.f / (1.f + __expf(-h1))) * h3;
        int row = (w >> 1) * 32 + mi * 16 + (lane >> 4) * 4 + rr;
        int col = (w & 1) * 32 + ni * 16 + (lane & 15);
        lact[row * 80 + col] = f2bf(a);
      }
  __syncthreads();
  const int row = tid >> 2, cq = (tid & 3) * 16;
  if (mbase + row < cnt) {
    unsigned short* qo = act + (size_t)(rbase + mbase + row) * ITR + n0 + cq;
    *(short8*)qo = *(const short8*)&lact[row * 80 + cq];
    *(short8*)(qo + 8) = *(const short8*)&lact[row * 80 + cq + 8];
  }
}

// ---------------- grouped GEMM fc2 + scaled atomic combine ---------------
__global__ __launch_bounds__(256, 2) void k_gemm2(
    const unsigned short* __restrict__ w2t, const unsigned short* __restrict__ act,
    const int* __restrict__ counts, const int* __restrict__ base,
    const int* __restrict__ toklist, const float* __restrict__ wlist,
    float* __restrict__ out) {
  const int e = blockIdx.z;
  const int cnt = counts[e];
  const int mbase = blockIdx.x * 64;
  if (mbase >= cnt) return;
  const int n0 = blockIdx.y * 64;
  const int rbase = base[e];

  __shared__ __align__(16) unsigned short lds[2 * 2 * 4096];  // dbuf x (A,W)
  const int tid = threadIdx.x;
  const int lane = tid & 63, w = tid >> 6;

  const unsigned short *srcA[2], *srcW[2];
  int dof[2];
#pragma unroll
  for (int i = 0; i < 2; ++i) {
    int cc = i * 256 + tid;
    int r = cc >> 3, b = cc & 7;
    int ko = (b ^ (r & 7)) * 8;
    int arow = rbase + mbase + r;
    if (arow > 2047) arow = 2047;
    srcA[i] = act + (size_t)arow * ITR + ko;
    srcW[i] = w2t + ((size_t)e * HID + n0 + r) * ITR + ko;
    dof[i] = i * 2048 + w * 512;
  }

  int offA[2][2], offW[2][2];
#pragma unroll
  for (int mi = 0; mi < 2; ++mi)
#pragma unroll
    for (int s = 0; s < 2; ++s) {
      int rowA = (w >> 1) * 32 + mi * 16 + (lane & 15);
      int rowW = (w & 1) * 32 + mi * 16 + (lane & 15);
      int kb = s * 4 + (lane >> 4);
      offA[mi][s] = rowA * 128 + ((kb ^ (rowA & 7)) << 4);
      offW[mi][s] = rowW * 128 + ((kb ^ (rowW & 7)) << 4);
    }

  f32x4 acc[2][2];
#pragma unroll
  for (int mi = 0; mi < 2; ++mi)
#pragma unroll
    for (int ni = 0; ni < 2; ++ni) acc[mi][ni] = (f32x4){0.f, 0.f, 0.f, 0.f};

#define STAGE2(buf, kt)                                           \
  {                                                               \
    int k0 = (kt) * 64;                                           \
    unsigned short* Lb = lds + (buf) * 8192;                      \
    _Pragma("unroll") for (int i = 0; i < 2; ++i) {               \
      gl_lds16(srcA[i] + k0, Lb + dof[i]);                        \
      gl_lds16(srcW[i] + k0, Lb + 4096 + dof[i]);                 \
    }                                                             \
  }

  STAGE2(0, 0);
  __syncthreads();
  int buf = 0;
  for (int kt = 0; kt < ITR / 64; ++kt) {
    if (kt + 1 < ITR / 64) STAGE2(buf ^ 1, kt + 1);
    const char* LA = (const char*)lds + buf * 16384;
    const char* LW = LA + 8192;
#pragma unroll
    for (int s = 0; s < 2; ++s) {
      short8 af[2], wf[2];
#pragma unroll
      for (int mi = 0; mi < 2; ++mi) af[mi] = *(const short8*)(LA + offA[mi][s]);
#pragma unroll
      for (int ni = 0; ni < 2; ++ni) wf[ni] = *(const short8*)(LW + offW[ni][s]);
#pragma unroll
      for (int ni = 0; ni < 2; ++ni)
#pragma unroll
        for (int mi = 0; mi < 2; ++mi)
          acc[mi][ni] = __builtin_amdgcn_mfma_f32_16x16x32_bf16(
              af[mi], wf[ni], acc[mi][ni], 0, 0, 0);
    }
    __syncthreads();
    buf ^= 1;
  }

  // epilogue: scale by routed prob, atomic combine (2 adds / out element)
#pragma unroll
  for (int mi = 0; mi < 2; ++mi)
#pragma unroll
    for (int rr = 0; rr < 4; ++rr) {
      int lr = (w >> 1) * 32 + mi * 16 + (lane >> 4) * 4 + rr;
      int grow = mbase + lr;
      if (grow < cnt) {
        float pv = wlist[rbase + grow];
        int tok = toklist[rbase + grow];
        float* orow = out + (size_t)tok * HID + n0 + (w & 1) * 32 + (lane & 15);
#pragma unroll
        for (int ni = 0; ni < 2; ++ni)
          atomicAdd(orow + ni * 16, acc[mi][ni][rr] * pv);
      }
    }
}

extern "C" void kernel_launch(void* const* d_in, const int* in_sizes, int n_in,
                              void* d_out, int out_size, void* d_ws,
                              size_t ws_size, hipStream_t stream) {
  (void)in_sizes; (void)n_in; (void)out_size; (void)ws_size;
  const float* x = (const float*)d_in[0];
  const float* rp = (const float*)d_in[1];
  const float* fc1 = (const float*)d_in[2];
  const float* fc2 = (const float*)d_in[3];
  const float* fc3 = (const float*)d_in[4];
  float* out = (float*)d_out;
  char* ws = (char*)d_ws;

  // ws layout (peak ~75.6 MB):
  int* counts = (int*)ws;                         // 32 B
  int* base = (int*)(ws + 256);                   // 32 B
  int* toklist = (int*)(ws + 4096);               // 8 KB
  float* wlist = (float*)(ws + 12288);            // 8 KB
  unsigned short* xb = (unsigned short*)(ws + 32768);           // 4 MB
  unsigned short* act = (unsigned short*)(ws + 4227072);        // 4 MB
  unsigned short* w3t = (unsigned short*)(ws + 8421376);        // 33.5 MB
  unsigned short* w12t = (unsigned short*)(ws + 41975808);      // 33.5 MB (w1t, later w2t)

  k_setup<<<2048, 256, 0, stream>>>(x, (unsigned int*)xb, out);
  k_router<<<1, 1024, 0, stream>>>(rp, counts, base, toklist, wlist);
  // fc1 [E][HID][ITR] -> w1t [E][ITR][HID]
  k_transcvt<<<dim3(HID / 64, ITR / 64, NEXP), 256, 0, stream>>>(fc1, w12t, HID, ITR);
  // fc3 [E][HID][ITR] -> w3t [E][ITR][HID]
  k_transcvt<<<dim3(HID / 64, ITR / 64, NEXP), 256, 0, stream>>>(fc3, w3t, HID, ITR);
  k_gemm13<<<dim3(16, ITR / 64, NEXP), 256, 0, stream>>>(w12t, w3t, xb, counts,
                                                         base, toklist, act);
  // fc2 [E][ITR][HID] -> w2t [E][HID][ITR] (reuses w1t space)
  k_transcvt<<<dim3(ITR / 64, HID / 64, NEXP), 256, 0, stream>>>(fc2, w12t, ITR, HID);
  k_gemm2<<<dim3(16, HID / 64, NEXP), 256, 0, stream>>>(w12t, act, counts, base,
                                                        toklist, wlist, out);
}

// Round 3
// 295.608 us; speedup vs baseline: 1.5407x; 1.2545x over previous
//
#include <hip/hip_runtime.h>

#define NEXP 8
#define NTOK 1024
#define HID 2048
#define ITR 1024

typedef __attribute__((ext_vector_type(8))) short short8;
typedef __attribute__((ext_vector_type(4))) float f32x4;

__device__ __forceinline__ unsigned short f2bf(float f) {
  unsigned u = __float_as_uint(f);
  u += 0x7fffu + ((u >> 16) & 1u);
  return (unsigned short)(u >> 16);
}

__device__ __forceinline__ void gl_lds16(const void* g, void* l) {
  __builtin_amdgcn_global_load_lds(
      (const __attribute__((address_space(1))) unsigned int*)g,
      (__attribute__((address_space(3))) unsigned int*)l, 16, 0, 0);
}

// ---------------- setup: zero out + x fp32->bf16 ----------------
__global__ __launch_bounds__(256) void k_setup(const float* __restrict__ x,
                                               unsigned int* __restrict__ xb,
                                               float* __restrict__ out) {
  int i = blockIdx.x * 256 + threadIdx.x;  // 524288 threads, 4 f32 each
  f32x4 z = {0.f, 0.f, 0.f, 0.f};
  *(f32x4*)(out + (size_t)i * 4) = z;
  f32x4 v = *(const f32x4*)(x + (size_t)i * 4);
  xb[(size_t)i * 2] = (unsigned)f2bf(v[0]) | ((unsigned)f2bf(v[1]) << 16);
  xb[(size_t)i * 2 + 1] = (unsigned)f2bf(v[2]) | ((unsigned)f2bf(v[3]) << 16);
}

// ---------------- router: top-2, flat compacted lists ----------------
__global__ __launch_bounds__(1024) void k_router(const float* __restrict__ rp,
                                                 int* __restrict__ counts,
                                                 int* __restrict__ base,
                                                 int* __restrict__ toklist,
                                                 float* __restrict__ wlist) {
  __shared__ int c[NEXP];
  __shared__ int sb[NEXP];
  int n = threadIdx.x;
  if (n < NEXP) c[n] = 0;
  __syncthreads();
  float r[NEXP];
#pragma unroll
  for (int e = 0; e < NEXP; ++e) r[e] = rp[n * NEXP + e];
  int i1 = 0;
  float m1 = r[0];
#pragma unroll
  for (int e = 1; e < NEXP; ++e)
    if (r[e] > m1) { m1 = r[e]; i1 = e; }
  int i2 = -1;
  float m2 = -3.4e38f;
#pragma unroll
  for (int e = 0; e < NEXP; ++e)
    if (e != i1 && r[e] > m2) { m2 = r[e]; i2 = e; }
  float p1 = 1.f / (1.f + __expf(m2 - m1));
  float p2 = 1.f - p1;
  int s1 = atomicAdd(&c[i1], 1);
  int s2 = atomicAdd(&c[i2], 1);
  __syncthreads();
  if (n == 0) {
    int a = 0;
#pragma unroll
    for (int e = 0; e < NEXP; ++e) { sb[e] = a; a += c[e]; }
  }
  __syncthreads();
  int q1 = sb[i1] + s1;
  toklist[q1] = n; wlist[q1] = p1;
  int q2 = sb[i2] + s2;
  toklist[q2] = n; wlist[q2] = p2;
  if (n < NEXP) { counts[n] = c[n]; base[n] = sb[n]; }
}

// ---------------- transpose-convert: fp32 [R][C] -> bf16 [C][R] ----------
__global__ __launch_bounds__(256) void k_transcvt(const float* __restrict__ in,
                                                  unsigned short* __restrict__ out,
                                                  int R, int C) {
  const int e = blockIdx.z;
  const float* src = in + (size_t)e * R * C;
  unsigned short* dst = out + (size_t)e * R * C;
  const int r0 = blockIdx.x * 64, c0 = blockIdx.y * 64;
  __shared__ unsigned short t[64][66];
  const int tid = threadIdx.x;
  const int r = tid >> 2, q = tid & 3;
  const float* p = src + (size_t)(r0 + r) * C + c0 + q * 4;
#pragma unroll
  for (int i = 0; i < 4; ++i) {
    f32x4 v = *(const f32x4*)(p + i * 16);
#pragma unroll
    for (int j = 0; j < 4; ++j) t[r][i * 16 + q * 4 + j] = f2bf(v[j]);
  }
  __syncthreads();
  const int cc = tid >> 2, rq = (tid & 3) * 16;
  unsigned short tmp[16];
#pragma unroll
  for (int i = 0; i < 16; ++i) tmp[i] = t[rq + i][cc];
  unsigned short* qo = dst + (size_t)(c0 + cc) * R + r0 + rq;
  *(short8*)qo = *(const short8*)tmp;
  *(short8*)(qo + 8) = *(const short8*)(tmp + 8);
}

// -------- grouped GEMM fc1/fc3 + swiglu: BM=256 BN=32 BK=64, XCD-pinned ---
__global__ __launch_bounds__(512, 4) void k_gemm13(
    const unsigned short* __restrict__ w1t, const unsigned short* __restrict__ w3t,
    const unsigned short* __restrict__ xb, const int* __restrict__ counts,
    const int* __restrict__ base, const int* __restrict__ toklist,
    unsigned short* __restrict__ act) {
  const int bid = blockIdx.x;      // 1024 blocks, e = bid&7 -> XCD pin
  const int e = bid & 7;
  const int t2 = bid >> 3;
  const int ntile = t2 & 31;       // 32 n-tiles of 32
  const int mtile = t2 >> 5;       // 0..3
  const int cnt = counts[e];
  const int mbase = mtile * 256;
  if (mbase >= cnt) return;
  const int n0 = ntile * 32;
  const int rbase = base[e];

  // per buf (ushort): A[256*64]=16384, W1[32*64]=2048, W3=2048 -> 20480 (40KB), x2 = 80KB
  __shared__ __align__(16) unsigned short lds[2 * 20480];
  const int tid = threadIdx.x;
  const int lane = tid & 63, w = tid >> 6;

  // A staging: 4 x 16B chunks/thread, source pre-XOR-swizzled, LDS linear
  const unsigned short* srcA[4];
  int dofA[4];
#pragma unroll
  for (int i = 0; i < 4; ++i) {
    int c = i * 512 + tid;
    int r = c >> 3, b = c & 7;
    int row = mbase + r;
    int tok = toklist[rbase + ((row < cnt) ? row : (cnt - 1))];
    srcA[i] = xb + (size_t)tok * HID + (b ^ (r & 7)) * 8;
    dofA[i] = (i * 512 + w * 64) * 8;  // ushort, wave-uniform
  }
  // W staging: 1 chunk/thread (waves 0-3: W1, 4-7: W3)
  const int mat = tid >> 8;
  const int cw = tid & 255;
  const int rw = cw >> 3, bw = cw & 7;
  const unsigned short* srcW =
      (mat ? w3t : w1t) + ((size_t)e * ITR + n0 + rw) * HID + (bw ^ (rw & 7)) * 8;
  const int dofW = 16384 + mat * 2048 + (w & 3) * 512;  // ushort, wave-uniform

  // fragment byte offsets
  int offA[2][2], offW[2][2];
#pragma unroll
  for (int i = 0; i < 2; ++i)
#pragma unroll
    for (int s = 0; s < 2; ++s) {
      int kb = s * 4 + (lane >> 4);
      int rowA = w * 32 + i * 16 + (lane & 15);
      offA[i][s] = rowA * 128 + ((kb ^ (rowA & 7)) << 4);
      int rowW = i * 16 + (lane & 15);
      offW[i][s] = 32768 + rowW * 128 + ((kb ^ (rowW & 7)) << 4);
    }

  f32x4 acc1[2][2], acc3[2][2];
#pragma unroll
  for (int mi = 0; mi < 2; ++mi)
#pragma unroll
    for (int ni = 0; ni < 2; ++ni) {
      acc1[mi][ni] = (f32x4){0.f, 0.f, 0.f, 0.f};
      acc3[mi][ni] = (f32x4){0.f, 0.f, 0.f, 0.f};
    }

#define STG13(buf, kt)                                      \
  {                                                         \
    int k0 = (kt) * 64;                                     \
    unsigned short* Lb = lds + (buf) * 20480;               \
    _Pragma("unroll") for (int i = 0; i < 4; ++i)           \
        gl_lds16(srcA[i] + k0, Lb + dofA[i]);               \
    gl_lds16(srcW + k0, Lb + dofW);                         \
  }

  STG13(0, 0);
  __syncthreads();
  int buf = 0;
  for (int kt = 0; kt < HID / 64; ++kt) {
    if (kt + 1 < HID / 64) STG13(buf ^ 1, kt + 1);
    const char* Lb = (const char*)(lds + buf * 20480);
#pragma unroll
    for (int s = 0; s < 2; ++s) {
      short8 af[2], w1f[2], w3f[2];
#pragma unroll
      for (int mi = 0; mi < 2; ++mi) af[mi] = *(const short8*)(Lb + offA[mi][s]);
#pragma unroll
      for (int ni = 0; ni < 2; ++ni) {
        w1f[ni] = *(const short8*)(Lb + offW[ni][s]);
        w3f[ni] = *(const short8*)(Lb + offW[ni][s] + 4096);
      }
#pragma unroll
      for (int ni = 0; ni < 2; ++ni)
#pragma unroll
        for (int mi = 0; mi < 2; ++mi) {
          acc1[mi][ni] = __builtin_amdgcn_mfma_f32_16x16x32_bf16(
              af[mi], w1f[ni], acc1[mi][ni], 0, 0, 0);
          acc3[mi][ni] = __builtin_amdgcn_mfma_f32_16x16x32_bf16(
              af[mi], w3f[ni], acc3[mi][ni], 0, 0, 0);
        }
    }
    __syncthreads();
    buf ^= 1;
  }

  // epilogue: swiglu -> LDS repack [256][40] -> coalesced 16B stores
  unsigned short* lact = lds;
#pragma unroll
  for (int mi = 0; mi < 2; ++mi)
#pragma unroll
    for (int ni = 0; ni < 2; ++ni)
#pragma unroll
      for (int rr = 0; rr < 4; ++rr) {
        float h1 = acc1[mi][ni][rr], h3 = acc3[mi][ni][rr];
        float a = h1 * (1.f / (1.f + __expf(-h1))) * h3;
        int row = w * 32 + mi * 16 + (lane >> 4) * 4 + rr;
        int col = ni * 16 + (lane & 15);
        lact[row * 40 + col] = f2bf(a);
      }
  __syncthreads();
#pragma unroll
  for (int p = 0; p < 2; ++p) {
    int row = p * 128 + (tid >> 2);
    int q = (tid & 3) * 8;
    if (mbase + row < cnt)
      *(short8*)(act + (size_t)(rbase + mbase + row) * ITR + n0 + q) =
          *(const short8*)&lact[row * 40 + q];
  }
}

// -------- grouped GEMM fc2 + scaled atomic combine: BM=256 BN=32 ---------
__global__ __launch_bounds__(512, 4) void k_gemm2(
    const unsigned short* __restrict__ w2t, const unsigned short* __restrict__ act,
    const int* __restrict__ counts, const int* __restrict__ base,
    const int* __restrict__ toklist, const float* __restrict__ wlist,
    float* __restrict__ out) {
  const int bid = blockIdx.x;      // 2048 blocks, e = bid&7 -> XCD pin
  const int e = bid & 7;
  const int t2 = bid >> 3;
  const int ntile = t2 & 63;       // 64 n-tiles of 32
  const int mtile = t2 >> 6;       // 0..3
  const int cnt = counts[e];
  const int mbase = mtile * 256;
  if (mbase >= cnt) return;
  const int n0 = ntile * 32;
  const int rbase = base[e];

  // per buf (ushort): A 16384 + W 2048 = 18432 (36KB), x2 = 72KB
  __shared__ __align__(16) unsigned short lds[2 * 18432];
  const int tid = threadIdx.x;
  const int lane = tid & 63, w = tid >> 6;

  const unsigned short* srcA[4];
  int dofA[4];
#pragma unroll
  for (int i = 0; i < 4; ++i) {
    int c = i * 512 + tid;
    int r = c >> 3, b = c & 7;
    int arow = rbase + mbase + r;
    if (arow > 2047) arow = 2047;
    srcA[i] = act + (size_t)arow * ITR + (b ^ (r & 7)) * 8;
    dofA[i] = (i * 512 + w * 64) * 8;
  }
  const int cw = tid & 255;
  const int rw = cw >> 3, bw = cw & 7;
  const unsigned short* srcW =
      w2t + ((size_t)e * HID + n0 + rw) * ITR + (bw ^ (rw & 7)) * 8;
  const int dofW = 16384 + (w & 3) * 512;

  int offA[2][2], offW[2][2];
#pragma unroll
  for (int i = 0; i < 2; ++i)
#pragma unroll
    for (int s = 0; s < 2; ++s) {
      int kb = s * 4 + (lane >> 4);
      int rowA = w * 32 + i * 16 + (lane & 15);
      offA[i][s] = rowA * 128 + ((kb ^ (rowA & 7)) << 4);
      int rowW = i * 16 + (lane & 15);
      offW[i][s] = 32768 + rowW * 128 + ((kb ^ (rowW & 7)) << 4);
    }

  f32x4 acc[2][2];
#pragma unroll
  for (int mi = 0; mi < 2; ++mi)
#pragma unroll
    for (int ni = 0; ni < 2; ++ni) acc[mi][ni] = (f32x4){0.f, 0.f, 0.f, 0.f};

#define STG2(buf, kt)                                       \
  {                                                         \
    int k0 = (kt) * 64;                                     \
    unsigned short* Lb = lds + (buf) * 18432;               \
    _Pragma("unroll") for (int i = 0; i < 4; ++i)           \
        gl_lds16(srcA[i] + k0, Lb + dofA[i]);               \
    if (w < 4) gl_lds16(srcW + k0, Lb + dofW);              \
  }

  STG2(0, 0);
  __syncthreads();
  int buf = 0;
  for (int kt = 0; kt < ITR / 64; ++kt) {
    if (kt + 1 < ITR / 64) STG2(buf ^ 1, kt + 1);
    const char* Lb = (const char*)(lds + buf * 18432);
#pragma unroll
    for (int s = 0; s < 2; ++s) {
      short8 af[2], wf[2];
#pragma unroll
      for (int mi = 0; mi < 2; ++mi) af[mi] = *(const short8*)(Lb + offA[mi][s]);
#pragma unroll
      for (int ni = 0; ni < 2; ++ni) wf[ni] = *(const short8*)(Lb + offW[ni][s]);
#pragma unroll
      for (int ni = 0; ni < 2; ++ni)
#pragma unroll
        for (int mi = 0; mi < 2; ++mi)
          acc[mi][ni] = __builtin_amdgcn_mfma_f32_16x16x32_bf16(
              af[mi], wf[ni], acc[mi][ni], 0, 0, 0);
    }
    __syncthreads();
    buf ^= 1;
  }

  // epilogue: scale by routed prob, atomic combine (2 adds / out element)
#pragma unroll
  for (int mi = 0; mi < 2; ++mi)
#pragma unroll
    for (int rr = 0; rr < 4; ++rr) {
      int lr = w * 32 + mi * 16 + (lane >> 4) * 4 + rr;
      int grow = mbase + lr;
      if (grow < cnt) {
        float pv = wlist[rbase + grow];
        int tok = toklist[rbase + grow];
        float* orow = out + (size_t)tok * HID + n0 + (lane & 15);
#pragma unroll
        for (int ni = 0; ni < 2; ++ni)
          atomicAdd(orow + ni * 16, acc[mi][ni][rr] * pv);
      }
    }
}

extern "C" void kernel_launch(void* const* d_in, const int* in_sizes, int n_in,
                              void* d_out, int out_size, void* d_ws,
                              size_t ws_size, hipStream_t stream) {
  (void)in_sizes; (void)n_in; (void)out_size; (void)ws_size;
  const float* x = (const float*)d_in[0];
  const float* rp = (const float*)d_in[1];
  const float* fc1 = (const float*)d_in[2];
  const float* fc2 = (const float*)d_in[3];
  const float* fc3 = (const float*)d_in[4];
  float* out = (float*)d_out;
  char* ws = (char*)d_ws;

  int* counts = (int*)ws;                         // 32 B
  int* base = (int*)(ws + 256);                   // 32 B
  int* toklist = (int*)(ws + 4096);               // 8 KB
  float* wlist = (float*)(ws + 12288);            // 8 KB
  unsigned short* xb = (unsigned short*)(ws + 32768);       // 4 MB
  unsigned short* act = (unsigned short*)(ws + 4227072);    // 4 MB
  unsigned short* w3t = (unsigned short*)(ws + 8421376);    // 33.5 MB
  unsigned short* w12t = (unsigned short*)(ws + 41975808);  // 33.5 MB (w1t, later w2t)

  k_setup<<<2048, 256, 0, stream>>>(x, (unsigned int*)xb, out);
  k_router<<<1, 1024, 0, stream>>>(rp, counts, base, toklist, wlist);
  k_transcvt<<<dim3(HID / 64, ITR / 64, NEXP), 256, 0, stream>>>(fc1, w12t, HID, ITR);
  k_transcvt<<<dim3(HID / 64, ITR / 64, NEXP), 256, 0, stream>>>(fc3, w3t, HID, ITR);
  k_gemm13<<<1024, 512, 0, stream>>>(w12t, w3t, xb, counts, base, toklist, act);
  k_transcvt<<<dim3(ITR / 64, HID / 64, NEXP), 256, 0, stream>>>(fc2, w12t, ITR, HID);
  k_gemm2<<<2048, 512, 0, stream>>>(w12t, act, counts, base, toklist, wlist, out);
}

// Round 5
// 282.611 us; speedup vs baseline: 1.6115x; 1.0460x over previous
//
#include <hip/hip_runtime.h>

#define NEXP 8
#define NTOK 1024
#define HID 2048
#define ITR 1024

typedef __attribute__((ext_vector_type(8))) short short8;
typedef __attribute__((ext_vector_type(4))) short short4v;
typedef __attribute__((ext_vector_type(4))) float f32x4;
typedef __attribute__((ext_vector_type(2))) float f32x2;
typedef __attribute__((ext_vector_type(2))) unsigned uint2v;

__device__ __forceinline__ unsigned short f2bf(float f) {
  unsigned u = __float_as_uint(f);
  u += 0x7fffu + ((u >> 16) & 1u);
  return (unsigned short)(u >> 16);
}

__device__ __forceinline__ void gl_lds16(const void* g, void* l) {
  __builtin_amdgcn_global_load_lds(
      (const __attribute__((address_space(1))) unsigned int*)g,
      (__attribute__((address_space(3))) unsigned int*)l, 16, 0, 0);
}

// ---------------- setup: zero out + x fp32->bf16 ----------------
__global__ __launch_bounds__(256) void k_setup(const float* __restrict__ x,
                                               unsigned int* __restrict__ xb,
                                               float* __restrict__ out) {
  int i = blockIdx.x * 256 + threadIdx.x;  // 524288 threads, 4 f32 each
  f32x4 z = {0.f, 0.f, 0.f, 0.f};
  *(f32x4*)(out + (size_t)i * 4) = z;
  f32x4 v = *(const f32x4*)(x + (size_t)i * 4);
  xb[(size_t)i * 2] = (unsigned)f2bf(v[0]) | ((unsigned)f2bf(v[1]) << 16);
  xb[(size_t)i * 2 + 1] = (unsigned)f2bf(v[2]) | ((unsigned)f2bf(v[3]) << 16);
}

// ---------------- router: top-2, flat compacted lists ----------------
__global__ __launch_bounds__(1024) void k_router(const float* __restrict__ rp,
                                                 int* __restrict__ counts,
                                                 int* __restrict__ base,
                                                 int* __restrict__ toklist,
                                                 float* __restrict__ wlist) {
  __shared__ int c[NEXP];
  __shared__ int sb[NEXP];
  int n = threadIdx.x;
  if (n < NEXP) c[n] = 0;
  __syncthreads();
  float r[NEXP];
#pragma unroll
  for (int e = 0; e < NEXP; ++e) r[e] = rp[n * NEXP + e];
  int i1 = 0;
  float m1 = r[0];
#pragma unroll
  for (int e = 1; e < NEXP; ++e)
    if (r[e] > m1) { m1 = r[e]; i1 = e; }
  int i2 = -1;
  float m2 = -3.4e38f;
#pragma unroll
  for (int e = 0; e < NEXP; ++e)
    if (e != i1 && r[e] > m2) { m2 = r[e]; i2 = e; }
  float p1 = 1.f / (1.f + __expf(m2 - m1));
  float p2 = 1.f - p1;
  int s1 = atomicAdd(&c[i1], 1);
  int s2 = atomicAdd(&c[i2], 1);
  __syncthreads();
  if (n == 0) {
    int a = 0;
#pragma unroll
    for (int e = 0; e < NEXP; ++e) { sb[e] = a; a += c[e]; }
  }
  __syncthreads();
  int q1 = sb[i1] + s1;
  toklist[q1] = n; wlist[q1] = p1;
  int q2 = sb[i2] + s2;
  toklist[q2] = n; wlist[q2] = p2;
  if (n < NEXP) { counts[n] = c[n]; base[n] = sb[n]; }
}

// ===== grouped GEMM fc1/fc3 + swiglu, fused fp32->bf16 W convert =====
// BM=256 BN=32 BK=64, 512 thr, XCD-pinned, dbuf.
// LDS per buf (ushort): A 16384 | W1 2048 | W3 2048  => 20480 (40KB), x2 = 80KB
__global__ __launch_bounds__(512, 4) void k_gemm13(
    const float* __restrict__ fc1, const float* __restrict__ fc3,
    const unsigned short* __restrict__ xb, const int* __restrict__ counts,
    const int* __restrict__ base, const int* __restrict__ toklist,
    unsigned short* __restrict__ act) {
  const int bid = blockIdx.x;  // 1024 blocks, e = bid&7 -> XCD pin
  const int e = bid & 7;
  const int t2 = bid >> 3;
  const int ntile = t2 & 31;   // 32 n-tiles of 32
  const int mtile = t2 >> 5;   // 0..3
  const int cnt = counts[e];
  const int mbase = mtile * 256;
  if (mbase >= cnt) return;
  const int n0t = ntile * 32;
  const int rbase = base[e];

  __shared__ __align__(16) unsigned short lds[2 * 20480];
  const int tid = threadIdx.x;
  const int lane = tid & 63, w = tid >> 6;

  // ---- A staging: 4x16B chunks/thread, source pre-XOR-swizzled ----
  const unsigned short* srcA[4];
  int dofA[4];
#pragma unroll
  for (int i = 0; i < 4; ++i) {
    int cc = i * 512 + tid;
    int r = cc >> 3, b = cc & 7;
    int row = mbase + r;
    int tok = toklist[rbase + ((row < cnt) ? row : (cnt - 1))];
    srcA[i] = xb + (size_t)tok * HID + (b ^ (r & 7)) * 8;
    dofA[i] = (i * 512 + w * 64) * 8;  // ushort, wave-uniform
  }

  // ---- W staging (reg -> cvt -> swizzled ds_write) ----
  // 256 threads per matrix; thread covers (k4..k4+3) x (n0,n0+1)
  const int mat = tid >> 8;  // 0: fc1, 1: fc3
  const int c8 = tid & 255;
  const int kq = c8 >> 4;         // 0..15, k4 = kq*4
  const int n0 = (c8 & 15) * 2;   // 0..30 even
  const float* wsrc = (mat ? fc3 : fc1) + (size_t)e * HID * ITR +
                      (size_t)(kq * 4) * ITR + n0t + n0;
  int wrb[2];
#pragma unroll
  for (int t = 0; t < 2; ++t) {
    int nn = n0 + t;
    wrb[t] = 32768 + mat * 4096 + nn * 128 + ((kq ^ (nn & 15)) << 3);
  }

  // ---- fragment byte offsets ----
  int offA[2][2], woff[2][2][2];
#pragma unroll
  for (int mi = 0; mi < 2; ++mi)
#pragma unroll
    for (int s = 0; s < 2; ++s) {
      int kb = s * 4 + (lane >> 4);
      int rowA = w * 32 + mi * 16 + (lane & 15);
      offA[mi][s] = rowA * 128 + ((kb ^ (rowA & 7)) << 4);
    }
#pragma unroll
  for (int ni = 0; ni < 2; ++ni)
#pragma unroll
    for (int s = 0; s < 2; ++s) {
      int n = ni * 16 + (lane & 15);
      int kb0 = s * 8 + (lane >> 4) * 2;
      woff[ni][s][0] = n * 128 + ((kb0 ^ (n & 15)) << 3);
      woff[ni][s][1] = n * 128 + (((kb0 + 1) ^ (n & 15)) << 3);
    }

  f32x4 acc1[2][2], acc3[2][2];
#pragma unroll
  for (int mi = 0; mi < 2; ++mi)
#pragma unroll
    for (int ni = 0; ni < 2; ++ni) {
      acc1[mi][ni] = (f32x4){0.f, 0.f, 0.f, 0.f};
      acc3[mi][ni] = (f32x4){0.f, 0.f, 0.f, 0.f};
    }

  float wvA[8], wvB[8];

#define STGA13(bb, kt)                                    \
  {                                                       \
    int k0 = (kt) * 64;                                   \
    unsigned short* Lb = lds + (bb) * 20480;              \
    _Pragma("unroll") for (int i = 0; i < 4; ++i)         \
        gl_lds16(srcA[i] + k0, Lb + dofA[i]);             \
  }
#define LOADW13(wv, kt)                                   \
  {                                                       \
    const float* g = wsrc + (size_t)(kt) * 64 * ITR;      \
    _Pragma("unroll") for (int j = 0; j < 4; ++j) {       \
      f32x2 vv = *(const f32x2*)(g + (size_t)j * ITR);    \
      wv[2 * j] = vv[0];                                  \
      wv[2 * j + 1] = vv[1];                              \
    }                                                     \
  }
#define CVTW13(wv, bb)                                                        \
  {                                                                           \
    _Pragma("unroll") for (int t = 0; t < 2; ++t) {                           \
      unsigned lo = (unsigned)f2bf(wv[t]) | ((unsigned)f2bf(wv[2 + t]) << 16);\
      unsigned hi =                                                           \
          (unsigned)f2bf(wv[4 + t]) | ((unsigned)f2bf(wv[6 + t]) << 16);      \
      uint2v v = {lo, hi};                                                    \
      *(uint2v*)((char*)lds + (bb) * 40960 + wrb[t]) = v;                     \
    }                                                                         \
  }
#define COMPUTE13(bb)                                                         \
  {                                                                           \
    const char* Lb = (const char*)lds + (bb) * 40960;                         \
    _Pragma("unroll") for (int s = 0; s < 2; ++s) {                           \
      short8 af[2];                                                           \
      _Pragma("unroll") for (int mi = 0; mi < 2; ++mi)                        \
          af[mi] = *(const short8*)(Lb + offA[mi][s]);                        \
      _Pragma("unroll") for (int ni = 0; ni < 2; ++ni) {                      \
        short4v l1 = *(const short4v*)(Lb + 32768 + woff[ni][s][0]);          \
        short4v h1 = *(const short4v*)(Lb + 32768 + woff[ni][s][1]);          \
        short4v l3 = *(const short4v*)(Lb + 36864 + woff[ni][s][0]);          \
        short4v h3 = *(const short4v*)(Lb + 36864 + woff[ni][s][1]);          \
        short8 w1f = __builtin_shufflevector(l1, h1, 0, 1, 2, 3, 4, 5, 6, 7); \
        short8 w3f = __builtin_shufflevector(l3, h3, 0, 1, 2, 3, 4, 5, 6, 7); \
        _Pragma("unroll") for (int mi = 0; mi < 2; ++mi) {                    \
          acc1[mi][ni] = __builtin_amdgcn_mfma_f32_16x16x32_bf16(             \
              af[mi], w1f, acc1[mi][ni], 0, 0, 0);                            \
          acc3[mi][ni] = __builtin_amdgcn_mfma_f32_16x16x32_bf16(             \
              af[mi], w3f, acc3[mi][ni], 0, 0, 0);                            \
        }                                                                     \
      }                                                                       \
    }                                                                         \
  }

  LOADW13(wvA, 0);
  STGA13(0, 0);
  CVTW13(wvA, 0);
  LOADW13(wvB, 1);
  __syncthreads();
  for (int kt = 0; kt < 32; kt += 2) {
    STGA13(1, kt + 1);
    CVTW13(wvB, 1);
    if (kt + 2 < 32) LOADW13(wvA, kt + 2);
    COMPUTE13(0);
    __syncthreads();
    if (kt + 2 < 32) {
      STGA13(0, kt + 2);
      CVTW13(wvA, 0);
    }
    if (kt + 3 < 32) LOADW13(wvB, kt + 3);
    COMPUTE13(1);
    __syncthreads();
  }

  // epilogue: swiglu -> LDS repack [256][40] -> coalesced 16B stores
  unsigned short* lact = lds;
#pragma unroll
  for (int mi = 0; mi < 2; ++mi)
#pragma unroll
    for (int ni = 0; ni < 2; ++ni)
#pragma unroll
      for (int rr = 0; rr < 4; ++rr) {
        float h1 = acc1[mi][ni][rr], h3 = acc3[mi][ni][rr];
        float a = h1 * (1.f / (1.f + __expf(-h1))) * h3;
        int row = w * 32 + mi * 16 + (lane >> 4) * 4 + rr;
        int col = ni * 16 + (lane & 15);
        lact[row * 40 + col] = f2bf(a);
      }
  __syncthreads();
#pragma unroll
  for (int p = 0; p < 2; ++p) {
    int row = p * 128 + (tid >> 2);
    int q = (tid & 3) * 8;
    if (mbase + row < cnt)
      *(short8*)(act + (size_t)(rbase + mbase + row) * ITR + n0t + q) =
          *(const short8*)&lact[row * 40 + q];
  }
}

// ===== grouped GEMM fc2 + scaled atomic combine, fused W convert =====
// BM=256 BN=32 BK=64, 512 thr. LDS/buf: A 16384 | W 2048 => 18432 (36KB) x2
__global__ __launch_bounds__(512, 4) void k_gemm2(
    const float* __restrict__ fc2, const unsigned short* __restrict__ act,
    const int* __restrict__ counts, const int* __restrict__ base,
    const int* __restrict__ toklist, const float* __restrict__ wlist,
    float* __restrict__ out) {
  const int bid = blockIdx.x;  // 2048 blocks, e = bid&7 -> XCD pin
  const int e = bid & 7;
  const int t2 = bid >> 3;
  const int ntile = t2 & 63;   // 64 n-tiles of 32
  const int mtile = t2 >> 6;   // 0..3
  const int cnt = counts[e];
  const int mbase = mtile * 256;
  if (mbase >= cnt) return;
  const int n0t = ntile * 32;
  const int rbase = base[e];

  __shared__ __align__(16) unsigned short lds[2 * 18432];
  const int tid = threadIdx.x;
  const int lane = tid & 63, w = tid >> 6;

  const unsigned short* srcA[4];
  int dofA[4];
#pragma unroll
  for (int i = 0; i < 4; ++i) {
    int cc = i * 512 + tid;
    int r = cc >> 3, b = cc & 7;
    int arow = rbase + mbase + r;
    if (arow > 2047) arow = 2047;
    srcA[i] = act + (size_t)arow * ITR + (b ^ (r & 7)) * 8;
    dofA[i] = (i * 512 + w * 64) * 8;
  }

  // W staging: thread covers (k4..k4+3) x (n0); 512 threads = 64k x 32n
  const int kq = tid >> 5;   // 0..15
  const int n0 = tid & 31;   // 0..31
  const float* wsrc =
      fc2 + (size_t)e * ITR * HID + (size_t)(kq * 4) * HID + n0t + n0;
  const int wrb = 32768 + n0 * 128 + ((kq ^ (n0 & 15)) << 3);

  int offA[2][2], woff[2][2][2];
#pragma unroll
  for (int mi = 0; mi < 2; ++mi)
#pragma unroll
    for (int s = 0; s < 2; ++s) {
      int kb = s * 4 + (lane >> 4);
      int rowA = w * 32 + mi * 16 + (lane & 15);
      offA[mi][s] = rowA * 128 + ((kb ^ (rowA & 7)) << 4);
    }
#pragma unroll
  for (int ni = 0; ni < 2; ++ni)
#pragma unroll
    for (int s = 0; s < 2; ++s) {
      int n = ni * 16 + (lane & 15);
      int kb0 = s * 8 + (lane >> 4) * 2;
      woff[ni][s][0] = n * 128 + ((kb0 ^ (n & 15)) << 3);
      woff[ni][s][1] = n * 128 + (((kb0 + 1) ^ (n & 15)) << 3);
    }

  f32x4 acc[2][2];
#pragma unroll
  for (int mi = 0; mi < 2; ++mi)
#pragma unroll
    for (int ni = 0; ni < 2; ++ni) acc[mi][ni] = (f32x4){0.f, 0.f, 0.f, 0.f};

  float wvA[4], wvB[4];

#define STGA2(bb, kt)                                     \
  {                                                       \
    int k0 = (kt) * 64;                                   \
    unsigned short* Lb = lds + (bb) * 18432;              \
    _Pragma("unroll") for (int i = 0; i < 4; ++i)         \
        gl_lds16(srcA[i] + k0, Lb + dofA[i]);             \
  }
#define LOADW2(wv, kt)                                    \
  {                                                       \
    const float* g = wsrc + (size_t)(kt) * 64 * HID;      \
    _Pragma("unroll") for (int j = 0; j < 4; ++j)         \
        wv[j] = g[(size_t)j * HID];                       \
  }
#define CVTW2(wv, bb)                                                       \
  {                                                                         \
    unsigned lo = (unsigned)f2bf(wv[0]) | ((unsigned)f2bf(wv[1]) << 16);    \
    unsigned hi = (unsigned)f2bf(wv[2]) | ((unsigned)f2bf(wv[3]) << 16);    \
    uint2v v = {lo, hi};                                                    \
    *(uint2v*)((char*)lds + (bb) * 36864 + wrb) = v;                        \
  }
#define COMPUTE2(bb)                                                          \
  {                                                                           \
    const char* Lb = (const char*)lds + (bb) * 36864;                         \
    _Pragma("unroll") for (int s = 0; s < 2; ++s) {                           \
      short8 af[2];                                                           \
      _Pragma("unroll") for (int mi = 0; mi < 2; ++mi)                        \
          af[mi] = *(const short8*)(Lb + offA[mi][s]);                        \
      _Pragma("unroll") for (int ni = 0; ni < 2; ++ni) {                      \
        short4v lw = *(const short4v*)(Lb + 32768 + woff[ni][s][0]);          \
        short4v hw = *(const short4v*)(Lb + 32768 + woff[ni][s][1]);          \
        short8 wf = __builtin_shufflevector(lw, hw, 0, 1, 2, 3, 4, 5, 6, 7);  \
        _Pragma("unroll") for (int mi = 0; mi < 2; ++mi)                      \
            acc[mi][ni] = __builtin_amdgcn_mfma_f32_16x16x32_bf16(            \
                af[mi], wf, acc[mi][ni], 0, 0, 0);                            \
      }                                                                       \
    }                                                                         \
  }

  LOADW2(wvA, 0);
  STGA2(0, 0);
  CVTW2(wvA, 0);
  LOADW2(wvB, 1);
  __syncthreads();
  for (int kt = 0; kt < 16; kt += 2) {
    STGA2(1, kt + 1);
    CVTW2(wvB, 1);
    if (kt + 2 < 16) LOADW2(wvA, kt + 2);
    COMPUTE2(0);
    __syncthreads();
    if (kt + 2 < 16) {
      STGA2(0, kt + 2);
      CVTW2(wvA, 0);
    }
    if (kt + 3 < 16) LOADW2(wvB, kt + 3);
    COMPUTE2(1);
    __syncthreads();
  }

  // epilogue: scale by routed prob, atomic combine (2 adds / out element)
#pragma unroll
  for (int mi = 0; mi < 2; ++mi)
#pragma unroll
    for (int rr = 0; rr < 4; ++rr) {
      int lr = w * 32 + mi * 16 + (lane >> 4) * 4 + rr;
      int grow = mbase + lr;
      if (grow < cnt) {
        float pv = wlist[rbase + grow];
        int tok = toklist[rbase + grow];
        float* orow = out + (size_t)tok * HID + n0t + (lane & 15);
#pragma unroll
        for (int ni = 0; ni < 2; ++ni)
          atomicAdd(orow + ni * 16, acc[mi][ni][rr] * pv);
      }
    }
}

extern "C" void kernel_launch(void* const* d_in, const int* in_sizes, int n_in,
                              void* d_out, int out_size, void* d_ws,
                              size_t ws_size, hipStream_t stream) {
  (void)in_sizes; (void)n_in; (void)out_size; (void)ws_size;
  const float* x = (const float*)d_in[0];
  const float* rp = (const float*)d_in[1];
  const float* fc1 = (const float*)d_in[2];
  const float* fc2 = (const float*)d_in[3];
  const float* fc3 = (const float*)d_in[4];
  float* out = (float*)d_out;
  char* ws = (char*)d_ws;

  int* counts = (int*)ws;                                // 32 B
  int* base = (int*)(ws + 256);                          // 32 B
  int* toklist = (int*)(ws + 4096);                      // 8 KB
  float* wlist = (float*)(ws + 12288);                   // 8 KB
  unsigned short* xb = (unsigned short*)(ws + 32768);    // 4 MB bf16 x
  unsigned short* act = (unsigned short*)(ws + 4227072); // 4 MB bf16 act

  k_setup<<<2048, 256, 0, stream>>>(x, (unsigned int*)xb, out);
  k_router<<<1, 1024, 0, stream>>>(rp, counts, base, toklist, wlist);
  k_gemm13<<<1024, 512, 0, stream>>>(fc1, fc3, xb, counts, base, toklist, act);
  k_gemm2<<<2048, 512, 0, stream>>>(fc2, act, counts, base, toklist, wlist, out);
}